// Round 4
// baseline (650.211 us; speedup 1.0000x reference)
//
#include <hip/hip_runtime.h>

typedef unsigned short u16;
typedef unsigned int   u32;
typedef __bf16  bf16x8 __attribute__((ext_vector_type(8)));
typedef float   f32x4  __attribute__((ext_vector_type(4)));
typedef u32     u32x4  __attribute__((ext_vector_type(4)));

#define NN 65536      // nodes
#define NE 524288     // edges
#define FD 256        // feature dim

typedef const __attribute__((address_space(1))) void* gas_p;
typedef __attribute__((address_space(3))) void* las_p;
#define GLDS16(g, l) __builtin_amdgcn_global_load_lds((gas_p)(const void*)(g), (las_p)(void*)(l), 16, 0, 0)

__device__ __forceinline__ u16 f2bf(float f){
  u32 u = __float_as_uint(f);
  u += 0x7fffu + ((u >> 16) & 1u);
  return (u16)(u >> 16);
}
__device__ __forceinline__ float bf2f(u32 lo16){
  return __uint_as_float(lo16 << 16);
}
__device__ __forceinline__ void acc8(float* a, uint4 v){
  a[0] += bf2f(v.x & 0xffffu); a[1] += bf2f(v.x >> 16);
  a[2] += bf2f(v.y & 0xffffu); a[3] += bf2f(v.y >> 16);
  a[4] += bf2f(v.z & 0xffffu); a[5] += bf2f(v.z >> 16);
  a[6] += bf2f(v.w & 0xffffu); a[7] += bf2f(v.w >> 16);
}
// swizzled u16 index within a [128][256] LDS tile: chunk(c>>3) low3 ^ row&7
__device__ __forceinline__ int lsw(int row, int c){
  return row * 256 + ((((c >> 3) ^ (row & 7)) & 31) << 3) + (c & 7);
}

// -------- weight prep (fp32 (K,256) -> bf16 (256,K)) + edge histogram --------
// prep blocks: 0..2559; hist blocks: 2560..4607 (merged to save a launch)
__global__ __launch_bounds__(256) void prep_hist_k(
    const float* __restrict__ w1a, const float* __restrict__ w1b,
    const float* __restrict__ w2a, const float* __restrict__ w2b,
    const float* __restrict__ w3a, const float* __restrict__ w3b,
    const float* __restrict__ w4a, const float* __restrict__ w4b,
    const float* __restrict__ wc1, u16* __restrict__ wT,
    const int* __restrict__ dst, int* __restrict__ deg)
{
  if (blockIdx.x >= 2560){
    int e = (blockIdx.x - 2560) * 256 + threadIdx.x;
    atomicAdd(&deg[dst[e]], 1);
    return;
  }
  int idx = blockIdx.x * 256 + threadIdx.x;   // 0 .. 655359
  const float* src; int base, K, local;
  if (idx < 131072){ src = w1a; base = 0; K = 512; local = idx; }
  else {
    local = idx - 131072;
    int j = local >> 16;       // 0..7
    local &= 65535;
    K = 256;
    base = 131072 + j * 65536;
    switch (j){
      case 0: src = w1b; break;
      case 1: src = w2a; break;
      case 2: src = w2b; break;
      case 3: src = w3a; break;
      case 4: src = w3b; break;
      case 5: src = w4a; break;
      case 6: src = w4b; break;
      default: src = wc1; break;
    }
  }
  int n = local & 255;
  int k = local >> 8;
  wT[base + n * K + k] = f2bf(src[k * 256 + n]);
}

// ---------------- CSR build ----------------
__global__ __launch_bounds__(1024) void scan_k(const int* __restrict__ deg, int* __restrict__ rs){
  __shared__ int part[1024];
  int t = threadIdx.x;
  int base = t * 64;
  int sum = 0;
  for (int i = 0; i < 64; ++i) sum += deg[base + i];
  part[t] = sum;
  __syncthreads();
  for (int off = 1; off < 1024; off <<= 1){
    int v = 0;
    if (t >= off) v = part[t - off];
    __syncthreads();
    part[t] += v;
    __syncthreads();
  }
  int run = part[t] - sum;          // exclusive prefix
  for (int i = 0; i < 64; ++i){ rs[base + i] = run; run += deg[base + i]; }
  if (t == 1023) rs[65536] = part[1023];
}

__global__ __launch_bounds__(256) void scat_k(
    const int* __restrict__ src, const int* __restrict__ dst,
    const int* __restrict__ rs, int* __restrict__ cursor, int* __restrict__ csr)
{
  int e = blockIdx.x * 256 + threadIdx.x;
  int d = dst[e];
  int pos = atomicAdd(&cursor[d], 1);
  csr[rs[d] + pos] = src[e];
}

// ------------- MFMA GEMM: C[M,256] = A[M,K] @ B[K,256], full-N tiles ---------
// Tile 128 x 256 per block (grid = M/128), 512 threads = 8 waves of 64x64.
// BK=64. A/B staged to LDS via async global_load_lds (16B chunks, XOR-swizzled).
// Epilogue bounces C through LDS (swizzled chunks) for full-line stores.
// MODE 0: plain. MODE 1: BN fold (p0=g,p1=be,p2=m,p3=v,p4=bb) + opt relu.
template<int AF32, int MODE, int RELU, int K>
__global__ __launch_bounds__(512) void gemm_k(
    const void* __restrict__ Ap, const u16* __restrict__ Bt,
    u16* __restrict__ C,
    const float* __restrict__ p0, const float* __restrict__ p1,
    const float* __restrict__ p2, const float* __restrict__ p3,
    const float* __restrict__ p4)
{
  __shared__ u16 lds[32768];           // 64 KB: staging 48 KB / epilogue 64 KB
  u16* As = lds;                       // 1024 chunks of 16B (128 rows x 8), swizzled
  u16* Bs = lds + 8192;                // 2048 chunks of 16B (256 rows x 8), swizzled
  const int t    = threadIdx.x;
  const int lane = t & 63;
  const int w    = t >> 6;             // 0..7
  const int wm   = w & 1;              // row half (0..1)
  const int wn   = w >> 1;             // col quarter (0..3)
  const int m0   = blockIdx.x * 128;
  const int mrow = lane & 15;
  const int quad = lane >> 4;

  f32x4 acc[4][4];
  const f32x4 zero = {0.f, 0.f, 0.f, 0.f};
  #pragma unroll
  for (int i = 0; i < 4; ++i)
    #pragma unroll
    for (int j = 0; j < 4; ++j) acc[i][j] = zero;

  const u16* Ab = (const u16*)Ap;
  const float* Af = (const float*)Ap;

  for (int k0 = 0; k0 < K; k0 += 64){
    // ---- stage A tile (128 rows x 64 k = 1024 chunks) ----
    if (AF32){
      #pragma unroll
      for (int i = 0; i < 2; ++i){
        int p   = i * 512 + t;
        int row = p >> 3;
        const float* s = Af + (size_t)(m0 + row) * K + k0 + (p & 7) * 8;
        float4 x0 = *(const float4*)s;
        float4 x1 = *(const float4*)(s + 4);
        union { u32x4 q; u16 h[8]; } u;
        u.h[0] = f2bf(x0.x); u.h[1] = f2bf(x0.y); u.h[2] = f2bf(x0.z); u.h[3] = f2bf(x0.w);
        u.h[4] = f2bf(x1.x); u.h[5] = f2bf(x1.y); u.h[6] = f2bf(x1.z); u.h[7] = f2bf(x1.w);
        int dst = (p & ~7) | ((p & 7) ^ (row & 7));
        *(u32x4*)&As[dst * 8] = u.q;
      }
    } else {
      #pragma unroll
      for (int i = 0; i < 2; ++i){
        int p   = i * 512 + t;
        int row = p >> 3;
        int ch  = (p & 7) ^ (row & 7);     // swizzled source chunk
        GLDS16(Ab + (size_t)(m0 + row) * K + k0 + ch * 8, &As[p * 8]);
      }
    }
    // ---- stage B tile (256 n-rows x 64 k = 2048 chunks) ----
    #pragma unroll
    for (int i = 0; i < 4; ++i){
      int p   = i * 512 + t;
      int row = p >> 3;
      int ch  = (p & 7) ^ (row & 7);
      GLDS16(Bt + (size_t)row * K + k0 + ch * 8, &Bs[p * 8]);
    }
    __syncthreads();
    // ---- compute: 2 k-steps of 32 ----
    #pragma unroll
    for (int ks = 0; ks < 2; ++ks){
      bf16x8 af[4], bq[4];
      #pragma unroll
      for (int mi = 0; mi < 4; ++mi){
        int r  = wm * 64 + mi * 16 + mrow;
        int ch = (quad + ks * 4) ^ (r & 7);
        af[mi] = *(const bf16x8*)&As[(r * 8 + ch) * 8];
      }
      #pragma unroll
      for (int ni = 0; ni < 4; ++ni){
        int rb = wn * 64 + ni * 16 + mrow;
        int ch = (quad + ks * 4) ^ (rb & 7);
        bq[ni] = *(const bf16x8*)&Bs[(rb * 8 + ch) * 8];
      }
      #pragma unroll
      for (int mi = 0; mi < 4; ++mi)
        #pragma unroll
        for (int ni = 0; ni < 4; ++ni)
          acc[mi][ni] = __builtin_amdgcn_mfma_f32_16x16x32_bf16(af[mi], bq[ni], acc[mi][ni], 0, 0, 0);
    }
    __syncthreads();
  }

  // ---- epilogue: acc -> LDS (swizzled chunks) -> coalesced 16B stores ----
  #pragma unroll
  for (int ni = 0; ni < 4; ++ni){
    int c  = wn * 64 + ni * 16 + mrow;    // global col (N=256 full per block)
    float scale = 1.f, shift = 0.f;
    if (MODE == 1){
      float s = p0[c] * rsqrtf(p3[c] + 1e-5f);
      scale = s;
      shift = (p4[c] - p2[c]) * s + p1[c];
    }
    #pragma unroll
    for (int mi = 0; mi < 4; ++mi){
      int rbase = wm * 64 + mi * 16 + quad * 4;
      #pragma unroll
      for (int reg = 0; reg < 4; ++reg){
        float v = acc[mi][ni][reg];
        if (MODE == 1){
          v = v * scale + shift;
          if (RELU) v = fmaxf(v, 0.f);
        }
        lds[lsw(rbase + reg, c)] = f2bf(v);
      }
    }
  }
  __syncthreads();
  #pragma unroll
  for (int i = 0; i < 8; ++i){
    int p  = i * 512 + t;       // 4096 chunks of 16B (128 rows x 32 chunks)
    int r  = p >> 5;
    int ch = p & 31;
    u32x4 q = *(const u32x4*)&lds[r * 256 + (ch ^ (r & 7)) * 8];
    *(u32x4*)&C[(size_t)(m0 + r) * 256 + ch * 8] = q;
  }
}

// ------- aggregation: u = (1+eps)*y[node] + sum_{in-edges} y[src] -------
// 2 nodes per wave (32 lanes x 16B = one 512B row per edge). Edge loop
// unrolled x4 with csr indices batch-loaded first -> 4 independent 16B
// loads in flight per lane (proven form; 8-deep regressed: +40 VGPR live
// state and the 8 index loads serialize ahead of the row loads).
// GATH=1: only the 6400 gathered rows. RAW=0: + bias, relu (MLP front).
// RAW=1: raw sum only (layer-4 order-swap: bias/relu applied after @wa).
template<int GATH, int RAW>
__global__ __launch_bounds__(256) void agg_k(
    const u16* __restrict__ y, const int* __restrict__ rs, const int* __restrict__ csr,
    const float* __restrict__ epsp, const float* __restrict__ bias,
    const int* __restrict__ gidx, u16* __restrict__ tout)
{
  int sub    = threadIdx.x >> 5;            // 0..7 node slot in block
  int lane32 = threadIdx.x & 31;
  int idx    = blockIdx.x * 8 + sub;
  int node;
  if (GATH) node = (idx / 200) * 2048 + gidx[idx];
  else      node = idx;
  int f0 = lane32 * 8;                      // 8 u16 = 16 B per lane
  float e1 = 1.0f + epsp[0];
  int s0 = rs[node], s1 = rs[node + 1];
  uint4 own = *(const uint4*)(y + (size_t)node * 256 + f0);   // issued early
  float a[8] = {0.f,0.f,0.f,0.f,0.f,0.f,0.f,0.f};
  int e = s0;
  for (; e + 4 <= s1; e += 4){
    int sa = csr[e], sb = csr[e+1], sc = csr[e+2], sd = csr[e+3];
    uint4 va = *(const uint4*)(y + (size_t)sa * 256 + f0);
    uint4 vb = *(const uint4*)(y + (size_t)sb * 256 + f0);
    uint4 vc = *(const uint4*)(y + (size_t)sc * 256 + f0);
    uint4 vd = *(const uint4*)(y + (size_t)sd * 256 + f0);
    acc8(a, va); acc8(a, vb); acc8(a, vc); acc8(a, vd);
  }
  for (; e < s1; ++e){
    int s = csr[e];
    acc8(a, *(const uint4*)(y + (size_t)s * 256 + f0));
  }
  float ow[8];
  ow[0] = bf2f(own.x & 0xffffu); ow[1] = bf2f(own.x >> 16);
  ow[2] = bf2f(own.y & 0xffffu); ow[3] = bf2f(own.y >> 16);
  ow[4] = bf2f(own.z & 0xffffu); ow[5] = bf2f(own.z >> 16);
  ow[6] = bf2f(own.w & 0xffffu); ow[7] = bf2f(own.w >> 16);
  float r[8];
  if (RAW){
    #pragma unroll
    for (int q = 0; q < 8; ++q) r[q] = e1 * ow[q] + a[q];
  } else {
    float4 b0 = *(const float4*)(bias + f0);
    float4 b1 = *(const float4*)(bias + f0 + 4);
    r[0] = fmaxf(e1 * ow[0] + a[0] + b0.x, 0.f);
    r[1] = fmaxf(e1 * ow[1] + a[1] + b0.y, 0.f);
    r[2] = fmaxf(e1 * ow[2] + a[2] + b0.z, 0.f);
    r[3] = fmaxf(e1 * ow[3] + a[3] + b0.w, 0.f);
    r[4] = fmaxf(e1 * ow[4] + a[4] + b1.x, 0.f);
    r[5] = fmaxf(e1 * ow[5] + a[5] + b1.y, 0.f);
    r[6] = fmaxf(e1 * ow[6] + a[6] + b1.z, 0.f);
    r[7] = fmaxf(e1 * ow[7] + a[7] + b1.w, 0.f);
  }
  uint4 o;
  o.x = (u32)f2bf(r[0]) | ((u32)f2bf(r[1]) << 16);
  o.y = (u32)f2bf(r[2]) | ((u32)f2bf(r[3]) << 16);
  o.z = (u32)f2bf(r[4]) | ((u32)f2bf(r[5]) << 16);
  o.w = (u32)f2bf(r[6]) | ((u32)f2bf(r[7]) << 16);
  *(uint4*)(tout + (size_t)idx * 256 + f0) = o;
}

// ---------- fused tail: u4 -> relu(@w4a+ba) -> BN(@w4b+bb) -> PReLU(@wc1+bc1)
//            -> out = @wc2 + bc2.   50 blocks x 128 rows, all intermediates
// stay in one 64 KB LDS tile (XOR-swizzled); B operands direct from L2.
// Replaces 3 GEMM dispatches + head_k (saves 3 launch gaps + round-trips).
__global__ __launch_bounds__(512) void tail_k(
    const u16* __restrict__ u4p, const u16* __restrict__ w4aT, const float* __restrict__ ba4,
    const u16* __restrict__ w4bT,
    const float* __restrict__ g, const float* __restrict__ be,
    const float* __restrict__ m, const float* __restrict__ v,
    const float* __restrict__ bb,
    const u16* __restrict__ wc1T, const float* __restrict__ bc1, const float* __restrict__ pa,
    const float* __restrict__ wc2, const float* __restrict__ bc2,
    float* __restrict__ out)
{
  __shared__ u16 lds[32768];           // one 128x256 bf16 tile, reused per stage
  const int t    = threadIdx.x;
  const int lane = t & 63;
  const int w    = t >> 6;
  const int wm   = w & 1;
  const int wn   = w >> 1;
  const int m0   = blockIdx.x * 128;
  const int mrow = lane & 15;
  const int quad = lane >> 4;
  const f32x4 zero = {0.f, 0.f, 0.f, 0.f};

  // ---- stage u4 tile (128 rows x 32 chunks), low3-XOR swizzle ----
  #pragma unroll
  for (int i = 0; i < 8; ++i){
    int p   = i * 512 + t;
    int row = p >> 5;
    int ch  = (p & 31) ^ (row & 7);
    GLDS16(u4p + (size_t)(m0 + row) * 256 + ch * 8, &lds[p * 8]);
  }
  __syncthreads();

  // ---- three chained GEMMs, epilogues write back to the same LDS tile ----
  #pragma unroll 1
  for (int stage = 0; stage < 3; ++stage){
    const u16* Bt = (stage == 0) ? w4aT : (stage == 1) ? w4bT : wc1T;
    f32x4 acc[4][4];
    #pragma unroll
    for (int i = 0; i < 4; ++i)
      #pragma unroll
      for (int j = 0; j < 4; ++j) acc[i][j] = zero;
    #pragma unroll
    for (int ks = 0; ks < 8; ++ks){
      bf16x8 af[4], bq[4];
      #pragma unroll
      for (int mi = 0; mi < 4; ++mi){
        int r    = wm * 64 + mi * 16 + mrow;
        int slot = (ks * 4 + quad) ^ (r & 7);
        af[mi] = *(const bf16x8*)&lds[r * 256 + slot * 8];
      }
      #pragma unroll
      for (int ni = 0; ni < 4; ++ni){
        int rb = wn * 64 + ni * 16 + mrow;
        bq[ni] = *(const bf16x8*)&Bt[(size_t)rb * 256 + ks * 32 + quad * 8];
      }
      #pragma unroll
      for (int mi = 0; mi < 4; ++mi)
        #pragma unroll
        for (int ni = 0; ni < 4; ++ni)
          acc[mi][ni] = __builtin_amdgcn_mfma_f32_16x16x32_bf16(af[mi], bq[ni], acc[mi][ni], 0, 0, 0);
    }
    __syncthreads();                    // all reads of old tile done
    #pragma unroll
    for (int ni = 0; ni < 4; ++ni){
      int c = wn * 64 + ni * 16 + mrow;
      float scale = 1.f, shift = 0.f, slope = 0.f; int prelu = 0, rel = 0;
      if (stage == 0){ shift = ba4[c]; rel = 1; }
      if (stage == 1){
        float s = g[c] * rsqrtf(v[c] + 1e-5f);
        scale = s;
        shift = (bb[c] - m[c]) * s + be[c];
      }
      if (stage == 2){ shift = bc1[c]; slope = pa[c]; prelu = 1; }
      #pragma unroll
      for (int mi = 0; mi < 4; ++mi){
        int rbase = wm * 64 + mi * 16 + quad * 4;
        #pragma unroll
        for (int reg = 0; reg < 4; ++reg){
          float val = acc[mi][ni][reg] * scale + shift;
          if (rel)   val = fmaxf(val, 0.f);
          if (prelu) val = val > 0.f ? val : slope * val;
          lds[lsw(rbase + reg, c)] = f2bf(val);
        }
      }
    }
    __syncthreads();
  }

  // ---- head: out[row,0..2] = hc[row,:] @ wc2 + bc2, one wave per 16 rows ----
  {
    int c0 = lane * 4;
    float4 wva = *(const float4*)(wc2 + c0 * 2);
    float4 wvb = *(const float4*)(wc2 + c0 * 2 + 4);
    float o0 = bc2[0], o1 = bc2[1];
    #pragma unroll 1
    for (int rr = 0; rr < 16; ++rr){
      int row = w * 16 + rr;
      int idxu = row * 256 + (((lane >> 1) ^ (row & 7)) << 3) + (c0 & 7);
      uint2 hv = *(const uint2*)&lds[idxu];
      float h0 = bf2f(hv.x & 0xffffu), h1 = bf2f(hv.x >> 16);
      float h2 = bf2f(hv.y & 0xffffu), h3 = bf2f(hv.y >> 16);
      float a0 = h0 * wva.x + h1 * wva.z + h2 * wvb.x + h3 * wvb.z;
      float a1 = h0 * wva.y + h1 * wva.w + h2 * wvb.y + h3 * wvb.w;
      #pragma unroll
      for (int off = 32; off > 0; off >>= 1){
        a0 += __shfl_xor(a0, off);
        a1 += __shfl_xor(a1, off);
      }
      if (lane == 0){
        out[(m0 + row) * 2]     = a0 + o0;
        out[(m0 + row) * 2 + 1] = a1 + o1;
      }
    }
  }
}

extern "C" void kernel_launch(void* const* d_in, const int* in_sizes, int n_in,
                              void* d_out, int out_size, void* d_ws, size_t ws_size,
                              hipStream_t stream)
{
  const float* feat = (const float*)d_in[0];
  const int*   A    = (const int*)d_in[1];
  const int*   h1id = (const int*)d_in[2];
  const float* eps[4] = {(const float*)d_in[4],  (const float*)d_in[13], (const float*)d_in[22], (const float*)d_in[31]};
  const float* wa [4] = {(const float*)d_in[5],  (const float*)d_in[14], (const float*)d_in[23], (const float*)d_in[32]};
  const float* ba [4] = {(const float*)d_in[6],  (const float*)d_in[15], (const float*)d_in[24], (const float*)d_in[33]};
  const float* wb [4] = {(const float*)d_in[7],  (const float*)d_in[16], (const float*)d_in[25], (const float*)d_in[34]};
  const float* bb [4] = {(const float*)d_in[8],  (const float*)d_in[17], (const float*)d_in[26], (const float*)d_in[35]};
  const float* g  [4] = {(const float*)d_in[9],  (const float*)d_in[18], (const float*)d_in[27], (const float*)d_in[36]};
  const float* be [4] = {(const float*)d_in[10], (const float*)d_in[19], (const float*)d_in[28], (const float*)d_in[37]};
  const float* m  [4] = {(const float*)d_in[11], (const float*)d_in[20], (const float*)d_in[29], (const float*)d_in[38]};
  const float* v  [4] = {(const float*)d_in[12], (const float*)d_in[21], (const float*)d_in[30], (const float*)d_in[39]};
  const float* wc1 = (const float*)d_in[40];
  const float* bc1 = (const float*)d_in[41];
  const float* pa  = (const float*)d_in[42];
  const float* wc2 = (const float*)d_in[43];
  const float* bc2 = (const float*)d_in[44];

  char* ws = (char*)d_ws;
  u16* wT     = (u16*)(ws + 0);            // 655360 u16 = 1,310,720 B
  int* deg    = (int*)(ws + 1310720);      // 262,144 B
  int* rs     = (int*)(ws + 1572864);      // 65537 ints, pad to 262,400 B
  int* cursor = (int*)(ws + 1835264);      // 262,144 B
  int* csr    = (int*)(ws + 2097408);      // 2,097,152 B
  u16* ybuf   = (u16*)(ws + 4194560);      // 32 MB
  u16* tbuf   = (u16*)(ws + 37748992);     // 32 MB
  u16* hbuf   = (u16*)(ws + 71303424);     // 32 MB
  u16* u4     = (u16*)(ws + 104857856);    // 3.2 MB  (raw agg, 6400 rows)

  // wT sub-offsets (u16 elements)
  u16* w1aT = wT;            // [256][512]
  u16* w1bT = wT + 131072;
  u16* w2aT = wT + 196608;
  u16* w2bT = wT + 262144;
  u16* w3aT = wT + 327680;
  u16* w3bT = wT + 393216;
  u16* w4aT = wT + 458752;
  u16* w4bT = wT + 524288;
  u16* wc1T = wT + 589824;

  hipMemsetAsync(deg, 0, 65536 * 4, stream);
  hipMemsetAsync(cursor, 0, 65536 * 4, stream);
  prep_hist_k<<<4608, 256, 0, stream>>>(wa[0], wb[0], wa[1], wb[1], wa[2], wb[2],
      wa[3], wb[3], wc1, wT, A + NE, deg);
  scan_k<<<1, 1024, 0, stream>>>(deg, rs);
  scat_k<<<NE / 256, 256, 0, stream>>>(A, A + NE, rs, cursor, csr);

  // layer 1: y1 = feat @ w1a (A fp32, K=512); t1 = relu(agg(y1)+ba1); h1 = relu(BN(t1@w1b+bb1))
  gemm_k<1,0,0,512><<<512, 512, 0, stream>>>(feat, w1aT, ybuf,
      nullptr, nullptr, nullptr, nullptr, nullptr);
  agg_k<0,0><<<NN / 8, 256, 0, stream>>>(ybuf, rs, csr, eps[0], ba[0], nullptr, tbuf);
  gemm_k<0,1,1,256><<<512, 512, 0, stream>>>(tbuf, w1bT, hbuf,
      g[0], be[0], m[0], v[0], bb[0]);

  // layers 2,3
  for (int l = 1; l <= 2; ++l){
    const u16* waT = (l == 1) ? w2aT : w3aT;
    const u16* wbT = (l == 1) ? w2bT : w3bT;
    gemm_k<0,0,0,256><<<512, 512, 0, stream>>>(hbuf, waT, ybuf,
        nullptr, nullptr, nullptr, nullptr, nullptr);
    agg_k<0,0><<<NN / 8, 256, 0, stream>>>(ybuf, rs, csr, eps[l], ba[l], nullptr, tbuf);
    gemm_k<0,1,1,256><<<512, 512, 0, stream>>>(tbuf, wbT, hbuf,
        g[l], be[l], m[l], v[l], bb[l]);
  }

  // layer 4 (order-swapped via linearity: agg(h3)@w4a == agg(h3@w4a)):
  //   u4 = (1+eps4)h3 + sum_in h3   (raw, only 6400 gathered rows)
  // then fused tail: relu(@w4a+ba4) -> BN(@w4b+bb4) -> PReLU(@wc1+bc1) -> @wc2+bc2
  agg_k<1,1><<<800, 256, 0, stream>>>(hbuf, rs, csr, eps[3], nullptr, h1id, u4);
  tail_k<<<50, 512, 0, stream>>>(u4, w4aT, ba[3], w4bT,
      g[3], be[3], m[3], v[3], bb[3],
      wc1T, bc1, pa, wc2, bc2, (float*)d_out);

  (void)in_sizes; (void)n_in; (void)out_size; (void)ws_size;
}

// Round 5
// 645.173 us; speedup vs baseline: 1.0078x; 1.0078x over previous
//
#include <hip/hip_runtime.h>

typedef unsigned short u16;
typedef unsigned int   u32;
typedef __bf16  bf16x8 __attribute__((ext_vector_type(8)));
typedef float   f32x4  __attribute__((ext_vector_type(4)));
typedef u32     u32x4  __attribute__((ext_vector_type(4)));

#define NN 65536      // nodes
#define NE 524288     // edges
#define FD 256        // feature dim

typedef const __attribute__((address_space(1))) void* gas_p;
typedef __attribute__((address_space(3))) void* las_p;
#define GLDS16(g, l) __builtin_amdgcn_global_load_lds((gas_p)(const void*)(g), (las_p)(void*)(l), 16, 0, 0)

__device__ __forceinline__ u16 f2bf(float f){
  u32 u = __float_as_uint(f);
  u += 0x7fffu + ((u >> 16) & 1u);
  return (u16)(u >> 16);
}
__device__ __forceinline__ float bf2f(u32 lo16){
  return __uint_as_float(lo16 << 16);
}
__device__ __forceinline__ void acc8(float* a, uint4 v){
  a[0] += bf2f(v.x & 0xffffu); a[1] += bf2f(v.x >> 16);
  a[2] += bf2f(v.y & 0xffffu); a[3] += bf2f(v.y >> 16);
  a[4] += bf2f(v.z & 0xffffu); a[5] += bf2f(v.z >> 16);
  a[6] += bf2f(v.w & 0xffffu); a[7] += bf2f(v.w >> 16);
}
// swizzled u16 index within a [128][256] LDS tile: chunk(c>>3) low3 ^ row&7
__device__ __forceinline__ int lsw(int row, int c){
  return row * 256 + ((((c >> 3) ^ (row & 7)) & 31) << 3) + (c & 7);
}

// -------- weight prep (fp32 (K,256) -> bf16 (256,K)) + edge histogram --------
// prep blocks: 0..2559; hist blocks: 2560..4607 (merged to save a launch)
__global__ __launch_bounds__(256) void prep_hist_k(
    const float* __restrict__ w1a, const float* __restrict__ w1b,
    const float* __restrict__ w2a, const float* __restrict__ w2b,
    const float* __restrict__ w3a, const float* __restrict__ w3b,
    const float* __restrict__ w4a, const float* __restrict__ w4b,
    const float* __restrict__ wc1, u16* __restrict__ wT,
    const int* __restrict__ dst, int* __restrict__ deg)
{
  if (blockIdx.x >= 2560){
    int e = (blockIdx.x - 2560) * 256 + threadIdx.x;
    atomicAdd(&deg[dst[e]], 1);
    return;
  }
  int idx = blockIdx.x * 256 + threadIdx.x;   // 0 .. 655359
  const float* src; int base, K, local;
  if (idx < 131072){ src = w1a; base = 0; K = 512; local = idx; }
  else {
    local = idx - 131072;
    int j = local >> 16;       // 0..7
    local &= 65535;
    K = 256;
    base = 131072 + j * 65536;
    switch (j){
      case 0: src = w1b; break;
      case 1: src = w2a; break;
      case 2: src = w2b; break;
      case 3: src = w3a; break;
      case 4: src = w3b; break;
      case 5: src = w4a; break;
      case 6: src = w4b; break;
      default: src = wc1; break;
    }
  }
  int n = local & 255;
  int k = local >> 8;
  wT[base + n * K + k] = f2bf(src[k * 256 + n]);
}

// ---------------- CSR build ----------------
__global__ __launch_bounds__(1024) void scan_k(const int* __restrict__ deg, int* __restrict__ rs){
  __shared__ int part[1024];
  int t = threadIdx.x;
  int base = t * 64;
  int sum = 0;
  for (int i = 0; i < 64; ++i) sum += deg[base + i];
  part[t] = sum;
  __syncthreads();
  for (int off = 1; off < 1024; off <<= 1){
    int v = 0;
    if (t >= off) v = part[t - off];
    __syncthreads();
    part[t] += v;
    __syncthreads();
  }
  int run = part[t] - sum;          // exclusive prefix
  for (int i = 0; i < 64; ++i){ rs[base + i] = run; run += deg[base + i]; }
  if (t == 1023) rs[65536] = part[1023];
}

__global__ __launch_bounds__(256) void scat_k(
    const int* __restrict__ src, const int* __restrict__ dst,
    const int* __restrict__ rs, int* __restrict__ cursor, int* __restrict__ csr)
{
  int e = blockIdx.x * 256 + threadIdx.x;
  int d = dst[e];
  int pos = atomicAdd(&cursor[d], 1);
  csr[rs[d] + pos] = src[e];
}

// ------------- MFMA GEMM: C[M,256] = A[M,K] @ B[K,256], full-N tiles ---------
// Tile 128 x 256 per block (grid = M/128), 512 threads = 8 waves of 64x64.
// BK=64. A/B staged to LDS via async global_load_lds (16B chunks, XOR-swizzled).
// Epilogue bounces C through LDS (swizzled chunks) for full-line stores.
// MODE 0: plain. MODE 1: BN fold (p0=g,p1=be,p2=m,p3=v,p4=bb) + opt relu.
template<int AF32, int MODE, int RELU, int K>
__global__ __launch_bounds__(512) void gemm_k(
    const void* __restrict__ Ap, const u16* __restrict__ Bt,
    u16* __restrict__ C,
    const float* __restrict__ p0, const float* __restrict__ p1,
    const float* __restrict__ p2, const float* __restrict__ p3,
    const float* __restrict__ p4)
{
  __shared__ u16 lds[32768];           // 64 KB: staging 48 KB / epilogue 64 KB
  u16* As = lds;                       // 1024 chunks of 16B (128 rows x 8), swizzled
  u16* Bs = lds + 8192;                // 2048 chunks of 16B (256 rows x 8), swizzled
  const int t    = threadIdx.x;
  const int lane = t & 63;
  const int w    = t >> 6;             // 0..7
  const int wm   = w & 1;              // row half (0..1)
  const int wn   = w >> 1;             // col quarter (0..3)
  const int m0   = blockIdx.x * 128;
  const int mrow = lane & 15;
  const int quad = lane >> 4;

  f32x4 acc[4][4];
  const f32x4 zero = {0.f, 0.f, 0.f, 0.f};
  #pragma unroll
  for (int i = 0; i < 4; ++i)
    #pragma unroll
    for (int j = 0; j < 4; ++j) acc[i][j] = zero;

  const u16* Ab = (const u16*)Ap;
  const float* Af = (const float*)Ap;

  for (int k0 = 0; k0 < K; k0 += 64){
    // ---- stage A tile (128 rows x 64 k = 1024 chunks) ----
    if (AF32){
      #pragma unroll
      for (int i = 0; i < 2; ++i){
        int p   = i * 512 + t;
        int row = p >> 3;
        const float* s = Af + (size_t)(m0 + row) * K + k0 + (p & 7) * 8;
        float4 x0 = *(const float4*)s;
        float4 x1 = *(const float4*)(s + 4);
        union { u32x4 q; u16 h[8]; } u;
        u.h[0] = f2bf(x0.x); u.h[1] = f2bf(x0.y); u.h[2] = f2bf(x0.z); u.h[3] = f2bf(x0.w);
        u.h[4] = f2bf(x1.x); u.h[5] = f2bf(x1.y); u.h[6] = f2bf(x1.z); u.h[7] = f2bf(x1.w);
        int dst = (p & ~7) | ((p & 7) ^ (row & 7));
        *(u32x4*)&As[dst * 8] = u.q;
      }
    } else {
      #pragma unroll
      for (int i = 0; i < 2; ++i){
        int p   = i * 512 + t;
        int row = p >> 3;
        int ch  = (p & 7) ^ (row & 7);     // swizzled source chunk
        GLDS16(Ab + (size_t)(m0 + row) * K + k0 + ch * 8, &As[p * 8]);
      }
    }
    // ---- stage B tile (256 n-rows x 64 k = 2048 chunks) ----
    #pragma unroll
    for (int i = 0; i < 4; ++i){
      int p   = i * 512 + t;
      int row = p >> 3;
      int ch  = (p & 7) ^ (row & 7);
      GLDS16(Bt + (size_t)row * K + k0 + ch * 8, &Bs[p * 8]);
    }
    __syncthreads();
    // ---- compute: 2 k-steps of 32 ----
    #pragma unroll
    for (int ks = 0; ks < 2; ++ks){
      bf16x8 af[4], bq[4];
      #pragma unroll
      for (int mi = 0; mi < 4; ++mi){
        int r  = wm * 64 + mi * 16 + mrow;
        int ch = (quad + ks * 4) ^ (r & 7);
        af[mi] = *(const bf16x8*)&As[(r * 8 + ch) * 8];
      }
      #pragma unroll
      for (int ni = 0; ni < 4; ++ni){
        int rb = wn * 64 + ni * 16 + mrow;
        int ch = (quad + ks * 4) ^ (rb & 7);
        bq[ni] = *(const bf16x8*)&Bs[(rb * 8 + ch) * 8];
      }
      #pragma unroll
      for (int mi = 0; mi < 4; ++mi)
        #pragma unroll
        for (int ni = 0; ni < 4; ++ni)
          acc[mi][ni] = __builtin_amdgcn_mfma_f32_16x16x32_bf16(af[mi], bq[ni], acc[mi][ni], 0, 0, 0);
    }
    __syncthreads();
  }

  // ---- epilogue: acc -> LDS (swizzled chunks) -> coalesced 16B stores ----
  #pragma unroll
  for (int ni = 0; ni < 4; ++ni){
    int c  = wn * 64 + ni * 16 + mrow;    // global col (N=256 full per block)
    float scale = 1.f, shift = 0.f;
    if (MODE == 1){
      float s = p0[c] * rsqrtf(p3[c] + 1e-5f);
      scale = s;
      shift = (p4[c] - p2[c]) * s + p1[c];
    }
    #pragma unroll
    for (int mi = 0; mi < 4; ++mi){
      int rbase = wm * 64 + mi * 16 + quad * 4;
      #pragma unroll
      for (int reg = 0; reg < 4; ++reg){
        float v = acc[mi][ni][reg];
        if (MODE == 1){
          v = v * scale + shift;
          if (RELU) v = fmaxf(v, 0.f);
        }
        lds[lsw(rbase + reg, c)] = f2bf(v);
      }
    }
  }
  __syncthreads();
  #pragma unroll
  for (int i = 0; i < 8; ++i){
    int p  = i * 512 + t;       // 4096 chunks of 16B (128 rows x 32 chunks)
    int r  = p >> 5;
    int ch = p & 31;
    u32x4 q = *(const u32x4*)&lds[r * 256 + (ch ^ (r & 7)) * 8];
    *(u32x4*)&C[(size_t)(m0 + r) * 256 + ch * 8] = q;
  }
}

// ---------- dual GEMM (linearity-swapped layer): C = relu(BN(relu(U@B1+ba) @ B2 + ...))
// Phase 1: t = relu(U @ B1 + ba)      (U,B1 staged via GLDS16, t -> LDS 64KB)
// Phase 2: C = relu(BN(t @ B2 + bb))  (t from LDS, B2 direct from L2)
// Skeleton verified in R2 (fuse2_k); only the epilogue formulas differ.
__global__ __launch_bounds__(512) void dual_k(
    const u16* __restrict__ Up, const u16* __restrict__ B1t,
    const float* __restrict__ ba,
    const u16* __restrict__ B2t,
    const float* __restrict__ g, const float* __restrict__ be,
    const float* __restrict__ m, const float* __restrict__ v,
    const float* __restrict__ bb,
    u16* __restrict__ C)
{
  __shared__ u16 lds[32768];           // staging 48 KB -> t 64 KB -> bounce
  u16* As = lds;
  u16* Bs = lds + 8192;
  const int t    = threadIdx.x;
  const int lane = t & 63;
  const int w    = t >> 6;
  const int wm   = w & 1;
  const int wn   = w >> 1;
  const int m0   = blockIdx.x * 128;
  const int mrow = lane & 15;
  const int quad = lane >> 4;

  const f32x4 zero = {0.f, 0.f, 0.f, 0.f};
  f32x4 acc[4][4];
  #pragma unroll
  for (int i = 0; i < 4; ++i)
    #pragma unroll
    for (int j = 0; j < 4; ++j) acc[i][j] = zero;

  // ---- phase 1: acc = U @ B1 (staged, K=256) ----
  for (int k0 = 0; k0 < 256; k0 += 64){
    #pragma unroll
    for (int i = 0; i < 2; ++i){
      int p   = i * 512 + t;
      int row = p >> 3;
      int ch  = (p & 7) ^ (row & 7);
      GLDS16(Up + (size_t)(m0 + row) * 256 + k0 + ch * 8, &As[p * 8]);
    }
    #pragma unroll
    for (int i = 0; i < 4; ++i){
      int p   = i * 512 + t;
      int row = p >> 3;
      int ch  = (p & 7) ^ (row & 7);
      GLDS16(B1t + (size_t)row * 256 + k0 + ch * 8, &Bs[p * 8]);
    }
    __syncthreads();
    #pragma unroll
    for (int ks = 0; ks < 2; ++ks){
      bf16x8 af[4], bq[4];
      #pragma unroll
      for (int mi = 0; mi < 4; ++mi){
        int r  = wm * 64 + mi * 16 + mrow;
        int ch = (quad + ks * 4) ^ (r & 7);
        af[mi] = *(const bf16x8*)&As[(r * 8 + ch) * 8];
      }
      #pragma unroll
      for (int ni = 0; ni < 4; ++ni){
        int rb = wn * 64 + ni * 16 + mrow;
        int ch = (quad + ks * 4) ^ (rb & 7);
        bq[ni] = *(const bf16x8*)&Bs[(rb * 8 + ch) * 8];
      }
      #pragma unroll
      for (int mi = 0; mi < 4; ++mi)
        #pragma unroll
        for (int ni = 0; ni < 4; ++ni)
          acc[mi][ni] = __builtin_amdgcn_mfma_f32_16x16x32_bf16(af[mi], bq[ni], acc[mi][ni], 0, 0, 0);
    }
    __syncthreads();
  }

  // ---- epi1: t = relu(acc + ba) -> LDS [128][256] swizzled ----
  #pragma unroll
  for (int ni = 0; ni < 4; ++ni){
    int c = wn * 64 + ni * 16 + mrow;
    float shift = ba[c];
    #pragma unroll
    for (int mi = 0; mi < 4; ++mi){
      int rbase = wm * 64 + mi * 16 + quad * 4;
      #pragma unroll
      for (int reg = 0; reg < 4; ++reg){
        float val = fmaxf(acc[mi][ni][reg] + shift, 0.f);
        lds[lsw(rbase + reg, c)] = f2bf(val);
      }
    }
  }
  __syncthreads();

  // ---- phase 2: acc2 = t @ B2 (t from LDS, B2 direct from L2) ----
  f32x4 acc2[4][4];
  #pragma unroll
  for (int i = 0; i < 4; ++i)
    #pragma unroll
    for (int j = 0; j < 4; ++j) acc2[i][j] = zero;
  #pragma unroll
  for (int ks = 0; ks < 8; ++ks){
    bf16x8 af[4], bq[4];
    #pragma unroll
    for (int mi = 0; mi < 4; ++mi){
      int r    = wm * 64 + mi * 16 + mrow;
      int slot = (ks * 4 + quad) ^ (r & 7);
      af[mi] = *(const bf16x8*)&lds[r * 256 + slot * 8];
    }
    #pragma unroll
    for (int ni = 0; ni < 4; ++ni){
      int rb = wn * 64 + ni * 16 + mrow;
      bq[ni] = *(const bf16x8*)&B2t[(size_t)rb * 256 + ks * 32 + quad * 8];
    }
    #pragma unroll
    for (int mi = 0; mi < 4; ++mi)
      #pragma unroll
      for (int ni = 0; ni < 4; ++ni)
        acc2[mi][ni] = __builtin_amdgcn_mfma_f32_16x16x32_bf16(af[mi], bq[ni], acc2[mi][ni], 0, 0, 0);
  }
  __syncthreads();

  // ---- epi2: C = relu(BN(acc2)) -> LDS (swizzled) -> coalesced stores ----
  #pragma unroll
  for (int ni = 0; ni < 4; ++ni){
    int c = wn * 64 + ni * 16 + mrow;
    float scale = g[c] * rsqrtf(v[c] + 1e-5f);
    float shift = (bb[c] - m[c]) * scale + be[c];
    #pragma unroll
    for (int mi = 0; mi < 4; ++mi){
      int rbase = wm * 64 + mi * 16 + quad * 4;
      #pragma unroll
      for (int reg = 0; reg < 4; ++reg){
        float val = fmaxf(acc2[mi][ni][reg] * scale + shift, 0.f);
        lds[lsw(rbase + reg, c)] = f2bf(val);
      }
    }
  }
  __syncthreads();
  #pragma unroll
  for (int i = 0; i < 8; ++i){
    int p  = i * 512 + t;
    int r  = p >> 5;
    int ch = p & 31;
    u32x4 q = *(const u32x4*)&lds[r * 256 + (ch ^ (r & 7)) * 8];
    *(u32x4*)&C[(size_t)(m0 + r) * 256 + ch * 8] = q;
  }
}

// ------- aggregation: u = (1+eps)*y[node] + sum_{in-edges} y[src] -------
// 2 nodes per wave (32 lanes x 16B = one 512B row per edge). Edge loop
// unrolled x4 with csr indices batch-loaded first (proven form).
// GATH=1: only the 6400 gathered rows. RAW=0: + bias, relu (MLP front).
// RAW=1: raw sum only (linearity swap: bias/relu applied after @wa).
template<int GATH, int RAW>
__global__ __launch_bounds__(256) void agg_k(
    const u16* __restrict__ y, const int* __restrict__ rs, const int* __restrict__ csr,
    const float* __restrict__ epsp, const float* __restrict__ bias,
    const int* __restrict__ gidx, u16* __restrict__ tout)
{
  int sub    = threadIdx.x >> 5;            // 0..7 node slot in block
  int lane32 = threadIdx.x & 31;
  int idx    = blockIdx.x * 8 + sub;
  int node;
  if (GATH) node = (idx / 200) * 2048 + gidx[idx];
  else      node = idx;
  int f0 = lane32 * 8;                      // 8 u16 = 16 B per lane
  float e1 = 1.0f + epsp[0];
  int s0 = rs[node], s1 = rs[node + 1];
  uint4 own = *(const uint4*)(y + (size_t)node * 256 + f0);   // issued early
  float a[8] = {0.f,0.f,0.f,0.f,0.f,0.f,0.f,0.f};
  int e = s0;
  for (; e + 4 <= s1; e += 4){
    int sa = csr[e], sb = csr[e+1], sc = csr[e+2], sd = csr[e+3];
    uint4 va = *(const uint4*)(y + (size_t)sa * 256 + f0);
    uint4 vb = *(const uint4*)(y + (size_t)sb * 256 + f0);
    uint4 vc = *(const uint4*)(y + (size_t)sc * 256 + f0);
    uint4 vd = *(const uint4*)(y + (size_t)sd * 256 + f0);
    acc8(a, va); acc8(a, vb); acc8(a, vc); acc8(a, vd);
  }
  for (; e < s1; ++e){
    int s = csr[e];
    acc8(a, *(const uint4*)(y + (size_t)s * 256 + f0));
  }
  float ow[8];
  ow[0] = bf2f(own.x & 0xffffu); ow[1] = bf2f(own.x >> 16);
  ow[2] = bf2f(own.y & 0xffffu); ow[3] = bf2f(own.y >> 16);
  ow[4] = bf2f(own.z & 0xffffu); ow[5] = bf2f(own.z >> 16);
  ow[6] = bf2f(own.w & 0xffffu); ow[7] = bf2f(own.w >> 16);
  float r[8];
  if (RAW){
    #pragma unroll
    for (int q = 0; q < 8; ++q) r[q] = e1 * ow[q] + a[q];
  } else {
    float4 b0 = *(const float4*)(bias + f0);
    float4 b1 = *(const float4*)(bias + f0 + 4);
    r[0] = fmaxf(e1 * ow[0] + a[0] + b0.x, 0.f);
    r[1] = fmaxf(e1 * ow[1] + a[1] + b0.y, 0.f);
    r[2] = fmaxf(e1 * ow[2] + a[2] + b0.z, 0.f);
    r[3] = fmaxf(e1 * ow[3] + a[3] + b0.w, 0.f);
    r[4] = fmaxf(e1 * ow[4] + a[4] + b1.x, 0.f);
    r[5] = fmaxf(e1 * ow[5] + a[5] + b1.y, 0.f);
    r[6] = fmaxf(e1 * ow[6] + a[6] + b1.z, 0.f);
    r[7] = fmaxf(e1 * ow[7] + a[7] + b1.w, 0.f);
  }
  uint4 o;
  o.x = (u32)f2bf(r[0]) | ((u32)f2bf(r[1]) << 16);
  o.y = (u32)f2bf(r[2]) | ((u32)f2bf(r[3]) << 16);
  o.z = (u32)f2bf(r[4]) | ((u32)f2bf(r[5]) << 16);
  o.w = (u32)f2bf(r[6]) | ((u32)f2bf(r[7]) << 16);
  *(uint4*)(tout + (size_t)idx * 256 + f0) = o;
}

// ---------- fused tail: u4 -> relu(@w4a+ba) -> BN(@w4b+bb) -> PReLU(@wc1+bc1)
//            -> out = @wc2 + bc2.   50 blocks x 128 rows, all intermediates
// stay in one 64 KB LDS tile (XOR-swizzled); B operands direct from L2.
__global__ __launch_bounds__(512) void tail_k(
    const u16* __restrict__ u4p, const u16* __restrict__ w4aT, const float* __restrict__ ba4,
    const u16* __restrict__ w4bT,
    const float* __restrict__ g, const float* __restrict__ be,
    const float* __restrict__ m, const float* __restrict__ v,
    const float* __restrict__ bb,
    const u16* __restrict__ wc1T, const float* __restrict__ bc1, const float* __restrict__ pa,
    const float* __restrict__ wc2, const float* __restrict__ bc2,
    float* __restrict__ out)
{
  __shared__ u16 lds[32768];           // one 128x256 bf16 tile, reused per stage
  const int t    = threadIdx.x;
  const int lane = t & 63;
  const int w    = t >> 6;
  const int wm   = w & 1;
  const int wn   = w >> 1;
  const int m0   = blockIdx.x * 128;
  const int mrow = lane & 15;
  const int quad = lane >> 4;
  const f32x4 zero = {0.f, 0.f, 0.f, 0.f};

  // ---- stage u4 tile (128 rows x 32 chunks), low3-XOR swizzle ----
  #pragma unroll
  for (int i = 0; i < 8; ++i){
    int p   = i * 512 + t;
    int row = p >> 5;
    int ch  = (p & 31) ^ (row & 7);
    GLDS16(u4p + (size_t)(m0 + row) * 256 + ch * 8, &lds[p * 8]);
  }
  __syncthreads();

  // ---- three chained GEMMs, epilogues write back to the same LDS tile ----
  #pragma unroll 1
  for (int stage = 0; stage < 3; ++stage){
    const u16* Bt = (stage == 0) ? w4aT : (stage == 1) ? w4bT : wc1T;
    f32x4 acc[4][4];
    #pragma unroll
    for (int i = 0; i < 4; ++i)
      #pragma unroll
      for (int j = 0; j < 4; ++j) acc[i][j] = zero;
    #pragma unroll
    for (int ks = 0; ks < 8; ++ks){
      bf16x8 af[4], bq[4];
      #pragma unroll
      for (int mi = 0; mi < 4; ++mi){
        int r    = wm * 64 + mi * 16 + mrow;
        int slot = (ks * 4 + quad) ^ (r & 7);
        af[mi] = *(const bf16x8*)&lds[r * 256 + slot * 8];
      }
      #pragma unroll
      for (int ni = 0; ni < 4; ++ni){
        int rb = wn * 64 + ni * 16 + mrow;
        bq[ni] = *(const bf16x8*)&Bt[(size_t)rb * 256 + ks * 32 + quad * 8];
      }
      #pragma unroll
      for (int mi = 0; mi < 4; ++mi)
        #pragma unroll
        for (int ni = 0; ni < 4; ++ni)
          acc[mi][ni] = __builtin_amdgcn_mfma_f32_16x16x32_bf16(af[mi], bq[ni], acc[mi][ni], 0, 0, 0);
    }
    __syncthreads();                    // all reads of old tile done
    #pragma unroll
    for (int ni = 0; ni < 4; ++ni){
      int c = wn * 64 + ni * 16 + mrow;
      float scale = 1.f, shift = 0.f, slope = 0.f; int prelu = 0, rel = 0;
      if (stage == 0){ shift = ba4[c]; rel = 1; }
      if (stage == 1){
        float s = g[c] * rsqrtf(v[c] + 1e-5f);
        scale = s;
        shift = (bb[c] - m[c]) * s + be[c];
      }
      if (stage == 2){ shift = bc1[c]; slope = pa[c]; prelu = 1; }
      #pragma unroll
      for (int mi = 0; mi < 4; ++mi){
        int rbase = wm * 64 + mi * 16 + quad * 4;
        #pragma unroll
        for (int reg = 0; reg < 4; ++reg){
          float val = acc[mi][ni][reg] * scale + shift;
          if (rel)   val = fmaxf(val, 0.f);
          if (prelu) val = val > 0.f ? val : slope * val;
          lds[lsw(rbase + reg, c)] = f2bf(val);
        }
      }
    }
    __syncthreads();
  }

  // ---- head: out[row,0..2] = hc[row,:] @ wc2 + bc2, one wave per 16 rows ----
  {
    int c0 = lane * 4;
    float4 wva = *(const float4*)(wc2 + c0 * 2);
    float4 wvb = *(const float4*)(wc2 + c0 * 2 + 4);
    float o0 = bc2[0], o1 = bc2[1];
    #pragma unroll 1
    for (int rr = 0; rr < 16; ++rr){
      int row = w * 16 + rr;
      int idxu = row * 256 + (((lane >> 1) ^ (row & 7)) << 3) + (c0 & 7);
      uint2 hv = *(const uint2*)&lds[idxu];
      float h0 = bf2f(hv.x & 0xffffu), h1 = bf2f(hv.x >> 16);
      float h2 = bf2f(hv.y & 0xffffu), h3 = bf2f(hv.y >> 16);
      float a0 = h0 * wva.x + h1 * wva.z + h2 * wvb.x + h3 * wvb.z;
      float a1 = h0 * wva.y + h1 * wva.w + h2 * wvb.y + h3 * wvb.w;
      #pragma unroll
      for (int off = 32; off > 0; off >>= 1){
        a0 += __shfl_xor(a0, off);
        a1 += __shfl_xor(a1, off);
      }
      if (lane == 0){
        out[(m0 + row) * 2]     = a0 + o0;
        out[(m0 + row) * 2 + 1] = a1 + o1;
      }
    }
  }
}

extern "C" void kernel_launch(void* const* d_in, const int* in_sizes, int n_in,
                              void* d_out, int out_size, void* d_ws, size_t ws_size,
                              hipStream_t stream)
{
  const float* feat = (const float*)d_in[0];
  const int*   A    = (const int*)d_in[1];
  const int*   h1id = (const int*)d_in[2];
  const float* eps[4] = {(const float*)d_in[4],  (const float*)d_in[13], (const float*)d_in[22], (const float*)d_in[31]};
  const float* wa [4] = {(const float*)d_in[5],  (const float*)d_in[14], (const float*)d_in[23], (const float*)d_in[32]};
  const float* ba [4] = {(const float*)d_in[6],  (const float*)d_in[15], (const float*)d_in[24], (const float*)d_in[33]};
  const float* wb [4] = {(const float*)d_in[7],  (const float*)d_in[16], (const float*)d_in[25], (const float*)d_in[34]};
  const float* bb [4] = {(const float*)d_in[8],  (const float*)d_in[17], (const float*)d_in[26], (const float*)d_in[35]};
  const float* g  [4] = {(const float*)d_in[9],  (const float*)d_in[18], (const float*)d_in[27], (const float*)d_in[36]};
  const float* be [4] = {(const float*)d_in[10], (const float*)d_in[19], (const float*)d_in[28], (const float*)d_in[37]};
  const float* m  [4] = {(const float*)d_in[11], (const float*)d_in[20], (const float*)d_in[29], (const float*)d_in[38]};
  const float* v  [4] = {(const float*)d_in[12], (const float*)d_in[21], (const float*)d_in[30], (const float*)d_in[39]};
  const float* wc1 = (const float*)d_in[40];
  const float* bc1 = (const float*)d_in[41];
  const float* pa  = (const float*)d_in[42];
  const float* wc2 = (const float*)d_in[43];
  const float* bc2 = (const float*)d_in[44];

  char* ws = (char*)d_ws;
  u16* wT     = (u16*)(ws + 0);            // 655360 u16 = 1,310,720 B
  int* deg    = (int*)(ws + 1310720);      // 262,144 B
  int* rs     = (int*)(ws + 1572864);      // 65537 ints, pad to 262,400 B
  int* cursor = (int*)(ws + 1835264);      // 262,144 B
  int* csr    = (int*)(ws + 2097408);      // 2,097,152 B
  u16* ybuf   = (u16*)(ws + 4194560);      // 32 MB (y1 / u-scratch)
  u16* tbuf   = (u16*)(ws + 37748992);     // 32 MB (t1)
  u16* hbuf   = (u16*)(ws + 71303424);     // 32 MB (h)
  u16* u4     = (u16*)(ws + 104857856);    // 3.2 MB  (raw agg, 6400 rows)

  // wT sub-offsets (u16 elements)
  u16* w1aT = wT;            // [256][512]
  u16* w1bT = wT + 131072;
  u16* w2aT = wT + 196608;
  u16* w2bT = wT + 262144;
  u16* w3aT = wT + 327680;
  u16* w3bT = wT + 393216;
  u16* w4aT = wT + 458752;
  u16* w4bT = wT + 524288;
  u16* wc1T = wT + 589824;

  hipMemsetAsync(deg, 0, 65536 * 4, stream);
  hipMemsetAsync(cursor, 0, 65536 * 4, stream);
  prep_hist_k<<<4608, 256, 0, stream>>>(wa[0], wb[0], wa[1], wb[1], wa[2], wb[2],
      wa[3], wb[3], wc1, wT, A + NE, deg);
  scan_k<<<1, 1024, 0, stream>>>(deg, rs);
  scat_k<<<NE / 256, 256, 0, stream>>>(A, A + NE, rs, cursor, csr);

  // layer 1: y1 = feat @ w1a (fp32, K=512); t1 = relu(agg(y1)+ba1); h1 = relu(BN(t1@w1b+bb1))
  gemm_k<1,0,0,512><<<512, 512, 0, stream>>>(feat, w1aT, ybuf,
      nullptr, nullptr, nullptr, nullptr, nullptr);
  agg_k<0,0><<<NN / 8, 256, 0, stream>>>(ybuf, rs, csr, eps[0], ba[0], nullptr, tbuf);
  gemm_k<0,1,1,256><<<512, 512, 0, stream>>>(tbuf, w1bT, hbuf,
      g[0], be[0], m[0], v[0], bb[0]);

  // layers 2,3 (linearity-swapped): u = agg_eps(h); h' = relu(BN(relu(u@wa+ba)@wb+bb))
  agg_k<0,1><<<NN / 8, 256, 0, stream>>>(hbuf, rs, csr, eps[1], nullptr, nullptr, ybuf);
  dual_k<<<512, 512, 0, stream>>>(ybuf, w2aT, ba[1], w2bT,
      g[1], be[1], m[1], v[1], bb[1], hbuf);
  agg_k<0,1><<<NN / 8, 256, 0, stream>>>(hbuf, rs, csr, eps[2], nullptr, nullptr, ybuf);
  dual_k<<<512, 512, 0, stream>>>(ybuf, w3aT, ba[2], w3bT,
      g[2], be[2], m[2], v[2], bb[2], hbuf);

  // layer 4 (order-swapped): u4 = agg_eps4(h3) at the 6400 gathered rows,
  // then fused tail: relu(@w4a+ba4) -> BN(@w4b+bb4) -> PReLU(@wc1+bc1) -> @wc2+bc2
  agg_k<1,1><<<800, 256, 0, stream>>>(hbuf, rs, csr, eps[3], nullptr, h1id, u4);
  tail_k<<<50, 512, 0, stream>>>(u4, w4aT, ba[3], w4bT,
      g[3], be[3], m[3], v[3], bb[3],
      wc1T, bc1, pa, wc2, bc2, (float*)d_out);

  (void)in_sizes; (void)n_in; (void)out_size; (void)ws_size;
}

// Round 6
// 636.038 us; speedup vs baseline: 1.0223x; 1.0144x over previous
//
#include <hip/hip_runtime.h>

typedef unsigned short u16;
typedef unsigned int   u32;
typedef __bf16  bf16x8 __attribute__((ext_vector_type(8)));
typedef float   f32x4  __attribute__((ext_vector_type(4)));
typedef u32     u32x4  __attribute__((ext_vector_type(4)));

#define NN 65536      // nodes
#define NE 524288     // edges
#define FD 256        // feature dim

typedef const __attribute__((address_space(1))) void* gas_p;
typedef __attribute__((address_space(3))) void* las_p;
#define GLDS16(g, l) __builtin_amdgcn_global_load_lds((gas_p)(const void*)(g), (las_p)(void*)(l), 16, 0, 0)

__device__ __forceinline__ u16 f2bf(float f){
  u32 u = __float_as_uint(f);
  u += 0x7fffu + ((u >> 16) & 1u);
  return (u16)(u >> 16);
}
__device__ __forceinline__ float bf2f(u32 lo16){
  return __uint_as_float(lo16 << 16);
}
__device__ __forceinline__ void acc8(float* a, uint4 v){
  a[0] += bf2f(v.x & 0xffffu); a[1] += bf2f(v.x >> 16);
  a[2] += bf2f(v.y & 0xffffu); a[3] += bf2f(v.y >> 16);
  a[4] += bf2f(v.z & 0xffffu); a[5] += bf2f(v.z >> 16);
  a[6] += bf2f(v.w & 0xffffu); a[7] += bf2f(v.w >> 16);
}
// swizzled u16 index within a [128][256] LDS tile: chunk(c>>3) low3 ^ row&7
__device__ __forceinline__ int lsw(int row, int c){
  return row * 256 + ((((c >> 3) ^ (row & 7)) & 31) << 3) + (c & 7);
}

// -------- weight prep (fp32 (K,256) -> bf16 (256,K)) + edge histogram --------
// prep blocks: 0..2559; hist blocks: 2560..4607 (merged to save a launch)
__global__ __launch_bounds__(256) void prep_hist_k(
    const float* __restrict__ w1a, const float* __restrict__ w1b,
    const float* __restrict__ w2a, const float* __restrict__ w2b,
    const float* __restrict__ w3a, const float* __restrict__ w3b,
    const float* __restrict__ w4a, const float* __restrict__ w4b,
    const float* __restrict__ wc1, u16* __restrict__ wT,
    const int* __restrict__ dst, int* __restrict__ deg)
{
  if (blockIdx.x >= 2560){
    int e = (blockIdx.x - 2560) * 256 + threadIdx.x;
    atomicAdd(&deg[dst[e]], 1);
    return;
  }
  int idx = blockIdx.x * 256 + threadIdx.x;   // 0 .. 655359
  const float* src; int base, K, local;
  if (idx < 131072){ src = w1a; base = 0; K = 512; local = idx; }
  else {
    local = idx - 131072;
    int j = local >> 16;       // 0..7
    local &= 65535;
    K = 256;
    base = 131072 + j * 65536;
    switch (j){
      case 0: src = w1b; break;
      case 1: src = w2a; break;
      case 2: src = w2b; break;
      case 3: src = w3a; break;
      case 4: src = w3b; break;
      case 5: src = w4a; break;
      case 6: src = w4b; break;
      default: src = wc1; break;
    }
  }
  int n = local & 255;
  int k = local >> 8;
  wT[base + n * K + k] = f2bf(src[k * 256 + n]);
}

// ---------------- CSR build ----------------
__global__ __launch_bounds__(1024) void scan_k(const int* __restrict__ deg, int* __restrict__ rs){
  __shared__ int part[1024];
  int t = threadIdx.x;
  int base = t * 64;
  int sum = 0;
  for (int i = 0; i < 64; ++i) sum += deg[base + i];
  part[t] = sum;
  __syncthreads();
  for (int off = 1; off < 1024; off <<= 1){
    int v = 0;
    if (t >= off) v = part[t - off];
    __syncthreads();
    part[t] += v;
    __syncthreads();
  }
  int run = part[t] - sum;          // exclusive prefix
  for (int i = 0; i < 64; ++i){ rs[base + i] = run; run += deg[base + i]; }
  if (t == 1023) rs[65536] = part[1023];
}

// ------- layer-1 GEMM (feat fp32, K=512) fused with CSR scatter --------
// blocks [0,512): 128x256 GEMM tiles (identical body to gemm_k<1,0,0,512>).
// blocks [512,1536): scat -- csr[rs[d] + cursor[d]++] = src[e], 512 edges/blk.
// scat is independent of the GEMM; merging lets its random atomics run
// under the GEMM's drain tail and removes one dispatch from the chain.
__global__ __launch_bounds__(512) void gemm1_scat_k(
    const float* __restrict__ Af, const u16* __restrict__ Bt,
    u16* __restrict__ C,
    const int* __restrict__ esrc, const int* __restrict__ edst,
    const int* __restrict__ rs, int* __restrict__ cursor, int* __restrict__ csr)
{
  __shared__ u16 lds[32768];
  if (blockIdx.x >= 512){
    int e = (blockIdx.x - 512) * 512 + threadIdx.x;
    int d = edst[e];
    int pos = atomicAdd(&cursor[d], 1);
    csr[rs[d] + pos] = esrc[e];
    return;
  }
  u16* As = lds;
  u16* Bs = lds + 8192;
  const int t    = threadIdx.x;
  const int lane = t & 63;
  const int w    = t >> 6;
  const int wm   = w & 1;
  const int wn   = w >> 1;
  const int m0   = blockIdx.x * 128;
  const int mrow = lane & 15;
  const int quad = lane >> 4;

  f32x4 acc[4][4];
  const f32x4 zero = {0.f, 0.f, 0.f, 0.f};
  #pragma unroll
  for (int i = 0; i < 4; ++i)
    #pragma unroll
    for (int j = 0; j < 4; ++j) acc[i][j] = zero;

  for (int k0 = 0; k0 < 512; k0 += 64){
    #pragma unroll
    for (int i = 0; i < 2; ++i){
      int p   = i * 512 + t;
      int row = p >> 3;
      const float* s = Af + (size_t)(m0 + row) * 512 + k0 + (p & 7) * 8;
      float4 x0 = *(const float4*)s;
      float4 x1 = *(const float4*)(s + 4);
      union { u32x4 q; u16 h[8]; } u;
      u.h[0] = f2bf(x0.x); u.h[1] = f2bf(x0.y); u.h[2] = f2bf(x0.z); u.h[3] = f2bf(x0.w);
      u.h[4] = f2bf(x1.x); u.h[5] = f2bf(x1.y); u.h[6] = f2bf(x1.z); u.h[7] = f2bf(x1.w);
      int dst = (p & ~7) | ((p & 7) ^ (row & 7));
      *(u32x4*)&As[dst * 8] = u.q;
    }
    #pragma unroll
    for (int i = 0; i < 4; ++i){
      int p   = i * 512 + t;
      int row = p >> 3;
      int ch  = (p & 7) ^ (row & 7);
      GLDS16(Bt + (size_t)row * 512 + k0 + ch * 8, &Bs[p * 8]);
    }
    __syncthreads();
    #pragma unroll
    for (int ks = 0; ks < 2; ++ks){
      bf16x8 af[4], bq[4];
      #pragma unroll
      for (int mi = 0; mi < 4; ++mi){
        int r  = wm * 64 + mi * 16 + mrow;
        int ch = (quad + ks * 4) ^ (r & 7);
        af[mi] = *(const bf16x8*)&As[(r * 8 + ch) * 8];
      }
      #pragma unroll
      for (int ni = 0; ni < 4; ++ni){
        int rb = wn * 64 + ni * 16 + mrow;
        int ch = (quad + ks * 4) ^ (rb & 7);
        bq[ni] = *(const bf16x8*)&Bs[(rb * 8 + ch) * 8];
      }
      #pragma unroll
      for (int mi = 0; mi < 4; ++mi)
        #pragma unroll
        for (int ni = 0; ni < 4; ++ni)
          acc[mi][ni] = __builtin_amdgcn_mfma_f32_16x16x32_bf16(af[mi], bq[ni], acc[mi][ni], 0, 0, 0);
    }
    __syncthreads();
  }

  #pragma unroll
  for (int ni = 0; ni < 4; ++ni){
    int c  = wn * 64 + ni * 16 + mrow;
    #pragma unroll
    for (int mi = 0; mi < 4; ++mi){
      int rbase = wm * 64 + mi * 16 + quad * 4;
      #pragma unroll
      for (int reg = 0; reg < 4; ++reg)
        lds[lsw(rbase + reg, c)] = f2bf(acc[mi][ni][reg]);
    }
  }
  __syncthreads();
  #pragma unroll
  for (int i = 0; i < 8; ++i){
    int p  = i * 512 + t;
    int r  = p >> 5;
    int ch = p & 31;
    u32x4 q = *(const u32x4*)&lds[r * 256 + (ch ^ (r & 7)) * 8];
    *(u32x4*)&C[(size_t)(m0 + r) * 256 + ch * 8] = q;
  }
}

// ------------- MFMA GEMM: C[M,256] = A[M,K] @ B[K,256], full-N tiles ---------
// MODE 0: plain. MODE 1: BN fold (p0=g,p1=be,p2=m,p3=v,p4=bb) + opt relu.
template<int MODE, int RELU, int K>
__global__ __launch_bounds__(512) void gemm_k(
    const void* __restrict__ Ap, const u16* __restrict__ Bt,
    u16* __restrict__ C,
    const float* __restrict__ p0, const float* __restrict__ p1,
    const float* __restrict__ p2, const float* __restrict__ p3,
    const float* __restrict__ p4)
{
  __shared__ u16 lds[32768];
  u16* As = lds;
  u16* Bs = lds + 8192;
  const int t    = threadIdx.x;
  const int lane = t & 63;
  const int w    = t >> 6;
  const int wm   = w & 1;
  const int wn   = w >> 1;
  const int m0   = blockIdx.x * 128;
  const int mrow = lane & 15;
  const int quad = lane >> 4;

  f32x4 acc[4][4];
  const f32x4 zero = {0.f, 0.f, 0.f, 0.f};
  #pragma unroll
  for (int i = 0; i < 4; ++i)
    #pragma unroll
    for (int j = 0; j < 4; ++j) acc[i][j] = zero;

  const u16* Ab = (const u16*)Ap;

  for (int k0 = 0; k0 < K; k0 += 64){
    #pragma unroll
    for (int i = 0; i < 2; ++i){
      int p   = i * 512 + t;
      int row = p >> 3;
      int ch  = (p & 7) ^ (row & 7);
      GLDS16(Ab + (size_t)(m0 + row) * K + k0 + ch * 8, &As[p * 8]);
    }
    #pragma unroll
    for (int i = 0; i < 4; ++i){
      int p   = i * 512 + t;
      int row = p >> 3;
      int ch  = (p & 7) ^ (row & 7);
      GLDS16(Bt + (size_t)row * K + k0 + ch * 8, &Bs[p * 8]);
    }
    __syncthreads();
    #pragma unroll
    for (int ks = 0; ks < 2; ++ks){
      bf16x8 af[4], bq[4];
      #pragma unroll
      for (int mi = 0; mi < 4; ++mi){
        int r  = wm * 64 + mi * 16 + mrow;
        int ch = (quad + ks * 4) ^ (r & 7);
        af[mi] = *(const bf16x8*)&As[(r * 8 + ch) * 8];
      }
      #pragma unroll
      for (int ni = 0; ni < 4; ++ni){
        int rb = wn * 64 + ni * 16 + mrow;
        int ch = (quad + ks * 4) ^ (rb & 7);
        bq[ni] = *(const bf16x8*)&Bs[(rb * 8 + ch) * 8];
      }
      #pragma unroll
      for (int mi = 0; mi < 4; ++mi)
        #pragma unroll
        for (int ni = 0; ni < 4; ++ni)
          acc[mi][ni] = __builtin_amdgcn_mfma_f32_16x16x32_bf16(af[mi], bq[ni], acc[mi][ni], 0, 0, 0);
    }
    __syncthreads();
  }

  #pragma unroll
  for (int ni = 0; ni < 4; ++ni){
    int c  = wn * 64 + ni * 16 + mrow;
    float scale = 1.f, shift = 0.f;
    if (MODE == 1){
      float s = p0[c] * rsqrtf(p3[c] + 1e-5f);
      scale = s;
      shift = (p4[c] - p2[c]) * s + p1[c];
    }
    #pragma unroll
    for (int mi = 0; mi < 4; ++mi){
      int rbase = wm * 64 + mi * 16 + quad * 4;
      #pragma unroll
      for (int reg = 0; reg < 4; ++reg){
        float v = acc[mi][ni][reg];
        if (MODE == 1){
          v = v * scale + shift;
          if (RELU) v = fmaxf(v, 0.f);
        }
        lds[lsw(rbase + reg, c)] = f2bf(v);
      }
    }
  }
  __syncthreads();
  #pragma unroll
  for (int i = 0; i < 8; ++i){
    int p  = i * 512 + t;
    int r  = p >> 5;
    int ch = p & 31;
    u32x4 q = *(const u32x4*)&lds[r * 256 + (ch ^ (r & 7)) * 8];
    *(u32x4*)&C[(size_t)(m0 + r) * 256 + ch * 8] = q;
  }
}

// ---------- dual GEMM (linearity-swapped layer) ----------
__global__ __launch_bounds__(512) void dual_k(
    const u16* __restrict__ Up, const u16* __restrict__ B1t,
    const float* __restrict__ ba,
    const u16* __restrict__ B2t,
    const float* __restrict__ g, const float* __restrict__ be,
    const float* __restrict__ m, const float* __restrict__ v,
    const float* __restrict__ bb,
    u16* __restrict__ C)
{
  __shared__ u16 lds[32768];
  u16* As = lds;
  u16* Bs = lds + 8192;
  const int t    = threadIdx.x;
  const int lane = t & 63;
  const int w    = t >> 6;
  const int wm   = w & 1;
  const int wn   = w >> 1;
  const int m0   = blockIdx.x * 128;
  const int mrow = lane & 15;
  const int quad = lane >> 4;

  const f32x4 zero = {0.f, 0.f, 0.f, 0.f};
  f32x4 acc[4][4];
  #pragma unroll
  for (int i = 0; i < 4; ++i)
    #pragma unroll
    for (int j = 0; j < 4; ++j) acc[i][j] = zero;

  for (int k0 = 0; k0 < 256; k0 += 64){
    #pragma unroll
    for (int i = 0; i < 2; ++i){
      int p   = i * 512 + t;
      int row = p >> 3;
      int ch  = (p & 7) ^ (row & 7);
      GLDS16(Up + (size_t)(m0 + row) * 256 + k0 + ch * 8, &As[p * 8]);
    }
    #pragma unroll
    for (int i = 0; i < 4; ++i){
      int p   = i * 512 + t;
      int row = p >> 3;
      int ch  = (p & 7) ^ (row & 7);
      GLDS16(B1t + (size_t)row * 256 + k0 + ch * 8, &Bs[p * 8]);
    }
    __syncthreads();
    #pragma unroll
    for (int ks = 0; ks < 2; ++ks){
      bf16x8 af[4], bq[4];
      #pragma unroll
      for (int mi = 0; mi < 4; ++mi){
        int r  = wm * 64 + mi * 16 + mrow;
        int ch = (quad + ks * 4) ^ (r & 7);
        af[mi] = *(const bf16x8*)&As[(r * 8 + ch) * 8];
      }
      #pragma unroll
      for (int ni = 0; ni < 4; ++ni){
        int rb = wn * 64 + ni * 16 + mrow;
        int ch = (quad + ks * 4) ^ (rb & 7);
        bq[ni] = *(const bf16x8*)&Bs[(rb * 8 + ch) * 8];
      }
      #pragma unroll
      for (int mi = 0; mi < 4; ++mi)
        #pragma unroll
        for (int ni = 0; ni < 4; ++ni)
          acc[mi][ni] = __builtin_amdgcn_mfma_f32_16x16x32_bf16(af[mi], bq[ni], acc[mi][ni], 0, 0, 0);
    }
    __syncthreads();
  }

  #pragma unroll
  for (int ni = 0; ni < 4; ++ni){
    int c = wn * 64 + ni * 16 + mrow;
    float shift = ba[c];
    #pragma unroll
    for (int mi = 0; mi < 4; ++mi){
      int rbase = wm * 64 + mi * 16 + quad * 4;
      #pragma unroll
      for (int reg = 0; reg < 4; ++reg){
        float val = fmaxf(acc[mi][ni][reg] + shift, 0.f);
        lds[lsw(rbase + reg, c)] = f2bf(val);
      }
    }
  }
  __syncthreads();

  f32x4 acc2[4][4];
  #pragma unroll
  for (int i = 0; i < 4; ++i)
    #pragma unroll
    for (int j = 0; j < 4; ++j) acc2[i][j] = zero;
  #pragma unroll
  for (int ks = 0; ks < 8; ++ks){
    bf16x8 af[4], bq[4];
    #pragma unroll
    for (int mi = 0; mi < 4; ++mi){
      int r    = wm * 64 + mi * 16 + mrow;
      int slot = (ks * 4 + quad) ^ (r & 7);
      af[mi] = *(const bf16x8*)&lds[r * 256 + slot * 8];
    }
    #pragma unroll
    for (int ni = 0; ni < 4; ++ni){
      int rb = wn * 64 + ni * 16 + mrow;
      bq[ni] = *(const bf16x8*)&B2t[(size_t)rb * 256 + ks * 32 + quad * 8];
    }
    #pragma unroll
    for (int mi = 0; mi < 4; ++mi)
      #pragma unroll
      for (int ni = 0; ni < 4; ++ni)
        acc2[mi][ni] = __builtin_amdgcn_mfma_f32_16x16x32_bf16(af[mi], bq[ni], acc2[mi][ni], 0, 0, 0);
  }
  __syncthreads();

  #pragma unroll
  for (int ni = 0; ni < 4; ++ni){
    int c = wn * 64 + ni * 16 + mrow;
    float scale = g[c] * rsqrtf(v[c] + 1e-5f);
    float shift = (bb[c] - m[c]) * scale + be[c];
    #pragma unroll
    for (int mi = 0; mi < 4; ++mi){
      int rbase = wm * 64 + mi * 16 + quad * 4;
      #pragma unroll
      for (int reg = 0; reg < 4; ++reg){
        float val = fmaxf(acc2[mi][ni][reg] * scale + shift, 0.f);
        lds[lsw(rbase + reg, c)] = f2bf(val);
      }
    }
  }
  __syncthreads();
  #pragma unroll
  for (int i = 0; i < 8; ++i){
    int p  = i * 512 + t;
    int r  = p >> 5;
    int ch = p & 31;
    u32x4 q = *(const u32x4*)&lds[r * 256 + (ch ^ (r & 7)) * 8];
    *(u32x4*)&C[(size_t)(m0 + r) * 256 + ch * 8] = q;
  }
}

// ------- aggregation: u = (1+eps)*y[node] + sum_{in-edges} y[src] -------
template<int GATH, int RAW>
__global__ __launch_bounds__(256) void agg_k(
    const u16* __restrict__ y, const int* __restrict__ rs, const int* __restrict__ csr,
    const float* __restrict__ epsp, const float* __restrict__ bias,
    const int* __restrict__ gidx, u16* __restrict__ tout)
{
  int sub    = threadIdx.x >> 5;            // 0..7 node slot in block
  int lane32 = threadIdx.x & 31;
  int idx    = blockIdx.x * 8 + sub;
  int node;
  if (GATH) node = (idx / 200) * 2048 + gidx[idx];
  else      node = idx;
  int f0 = lane32 * 8;                      // 8 u16 = 16 B per lane
  float e1 = 1.0f + epsp[0];
  int s0 = rs[node], s1 = rs[node + 1];
  uint4 own = *(const uint4*)(y + (size_t)node * 256 + f0);   // issued early
  float a[8] = {0.f,0.f,0.f,0.f,0.f,0.f,0.f,0.f};
  int e = s0;
  for (; e + 4 <= s1; e += 4){
    int sa = csr[e], sb = csr[e+1], sc = csr[e+2], sd = csr[e+3];
    uint4 va = *(const uint4*)(y + (size_t)sa * 256 + f0);
    uint4 vb = *(const uint4*)(y + (size_t)sb * 256 + f0);
    uint4 vc = *(const uint4*)(y + (size_t)sc * 256 + f0);
    uint4 vd = *(const uint4*)(y + (size_t)sd * 256 + f0);
    acc8(a, va); acc8(a, vb); acc8(a, vc); acc8(a, vd);
  }
  for (; e < s1; ++e){
    int s = csr[e];
    acc8(a, *(const uint4*)(y + (size_t)s * 256 + f0));
  }
  float ow[8];
  ow[0] = bf2f(own.x & 0xffffu); ow[1] = bf2f(own.x >> 16);
  ow[2] = bf2f(own.y & 0xffffu); ow[3] = bf2f(own.y >> 16);
  ow[4] = bf2f(own.z & 0xffffu); ow[5] = bf2f(own.z >> 16);
  ow[6] = bf2f(own.w & 0xffffu); ow[7] = bf2f(own.w >> 16);
  float r[8];
  if (RAW){
    #pragma unroll
    for (int q = 0; q < 8; ++q) r[q] = e1 * ow[q] + a[q];
  } else {
    float4 b0 = *(const float4*)(bias + f0);
    float4 b1 = *(const float4*)(bias + f0 + 4);
    r[0] = fmaxf(e1 * ow[0] + a[0] + b0.x, 0.f);
    r[1] = fmaxf(e1 * ow[1] + a[1] + b0.y, 0.f);
    r[2] = fmaxf(e1 * ow[2] + a[2] + b0.z, 0.f);
    r[3] = fmaxf(e1 * ow[3] + a[3] + b0.w, 0.f);
    r[4] = fmaxf(e1 * ow[4] + a[4] + b1.x, 0.f);
    r[5] = fmaxf(e1 * ow[5] + a[5] + b1.y, 0.f);
    r[6] = fmaxf(e1 * ow[6] + a[6] + b1.z, 0.f);
    r[7] = fmaxf(e1 * ow[7] + a[7] + b1.w, 0.f);
  }
  uint4 o;
  o.x = (u32)f2bf(r[0]) | ((u32)f2bf(r[1]) << 16);
  o.y = (u32)f2bf(r[2]) | ((u32)f2bf(r[3]) << 16);
  o.z = (u32)f2bf(r[4]) | ((u32)f2bf(r[5]) << 16);
  o.w = (u32)f2bf(r[6]) | ((u32)f2bf(r[7]) << 16);
  *(uint4*)(tout + (size_t)idx * 256 + f0) = o;
}

// ---------- fused tail: u4 -> relu(@w4a+ba) -> BN(@w4b+bb) -> PReLU(@wc1+bc1)
//            -> out = @wc2 + bc2.   50 blocks x 128 rows, in-LDS.
__global__ __launch_bounds__(512) void tail_k(
    const u16* __restrict__ u4p, const u16* __restrict__ w4aT, const float* __restrict__ ba4,
    const u16* __restrict__ w4bT,
    const float* __restrict__ g, const float* __restrict__ be,
    const float* __restrict__ m, const float* __restrict__ v,
    const float* __restrict__ bb,
    const u16* __restrict__ wc1T, const float* __restrict__ bc1, const float* __restrict__ pa,
    const float* __restrict__ wc2, const float* __restrict__ bc2,
    float* __restrict__ out)
{
  __shared__ u16 lds[32768];
  const int t    = threadIdx.x;
  const int lane = t & 63;
  const int w    = t >> 6;
  const int wm   = w & 1;
  const int wn   = w >> 1;
  const int m0   = blockIdx.x * 128;
  const int mrow = lane & 15;
  const int quad = lane >> 4;
  const f32x4 zero = {0.f, 0.f, 0.f, 0.f};

  #pragma unroll
  for (int i = 0; i < 8; ++i){
    int p   = i * 512 + t;
    int row = p >> 5;
    int ch  = (p & 31) ^ (row & 7);
    GLDS16(u4p + (size_t)(m0 + row) * 256 + ch * 8, &lds[p * 8]);
  }
  __syncthreads();

  #pragma unroll 1
  for (int stage = 0; stage < 3; ++stage){
    const u16* Bt = (stage == 0) ? w4aT : (stage == 1) ? w4bT : wc1T;
    f32x4 acc[4][4];
    #pragma unroll
    for (int i = 0; i < 4; ++i)
      #pragma unroll
      for (int j = 0; j < 4; ++j) acc[i][j] = zero;
    #pragma unroll
    for (int ks = 0; ks < 8; ++ks){
      bf16x8 af[4], bq[4];
      #pragma unroll
      for (int mi = 0; mi < 4; ++mi){
        int r    = wm * 64 + mi * 16 + mrow;
        int slot = (ks * 4 + quad) ^ (r & 7);
        af[mi] = *(const bf16x8*)&lds[r * 256 + slot * 8];
      }
      #pragma unroll
      for (int ni = 0; ni < 4; ++ni){
        int rb = wn * 64 + ni * 16 + mrow;
        bq[ni] = *(const bf16x8*)&Bt[(size_t)rb * 256 + ks * 32 + quad * 8];
      }
      #pragma unroll
      for (int mi = 0; mi < 4; ++mi)
        #pragma unroll
        for (int ni = 0; ni < 4; ++ni)
          acc[mi][ni] = __builtin_amdgcn_mfma_f32_16x16x32_bf16(af[mi], bq[ni], acc[mi][ni], 0, 0, 0);
    }
    __syncthreads();
    #pragma unroll
    for (int ni = 0; ni < 4; ++ni){
      int c = wn * 64 + ni * 16 + mrow;
      float scale = 1.f, shift = 0.f, slope = 0.f; int prelu = 0, rel = 0;
      if (stage == 0){ shift = ba4[c]; rel = 1; }
      if (stage == 1){
        float s = g[c] * rsqrtf(v[c] + 1e-5f);
        scale = s;
        shift = (bb[c] - m[c]) * s + be[c];
      }
      if (stage == 2){ shift = bc1[c]; slope = pa[c]; prelu = 1; }
      #pragma unroll
      for (int mi = 0; mi < 4; ++mi){
        int rbase = wm * 64 + mi * 16 + quad * 4;
        #pragma unroll
        for (int reg = 0; reg < 4; ++reg){
          float val = acc[mi][ni][reg] * scale + shift;
          if (rel)   val = fmaxf(val, 0.f);
          if (prelu) val = val > 0.f ? val : slope * val;
          lds[lsw(rbase + reg, c)] = f2bf(val);
        }
      }
    }
    __syncthreads();
  }

  {
    int c0 = lane * 4;
    float4 wva = *(const float4*)(wc2 + c0 * 2);
    float4 wvb = *(const float4*)(wc2 + c0 * 2 + 4);
    float o0 = bc2[0], o1 = bc2[1];
    #pragma unroll 1
    for (int rr = 0; rr < 16; ++rr){
      int row = w * 16 + rr;
      int idxu = row * 256 + (((lane >> 1) ^ (row & 7)) << 3) + (c0 & 7);
      uint2 hv = *(const uint2*)&lds[idxu];
      float h0 = bf2f(hv.x & 0xffffu), h1 = bf2f(hv.x >> 16);
      float h2 = bf2f(hv.y & 0xffffu), h3 = bf2f(hv.y >> 16);
      float a0 = h0 * wva.x + h1 * wva.z + h2 * wvb.x + h3 * wvb.z;
      float a1 = h0 * wva.y + h1 * wva.w + h2 * wvb.y + h3 * wvb.w;
      #pragma unroll
      for (int off = 32; off > 0; off >>= 1){
        a0 += __shfl_xor(a0, off);
        a1 += __shfl_xor(a1, off);
      }
      if (lane == 0){
        out[(m0 + row) * 2]     = a0 + o0;
        out[(m0 + row) * 2 + 1] = a1 + o1;
      }
    }
  }
}

extern "C" void kernel_launch(void* const* d_in, const int* in_sizes, int n_in,
                              void* d_out, int out_size, void* d_ws, size_t ws_size,
                              hipStream_t stream)
{
  const float* feat = (const float*)d_in[0];
  const int*   A    = (const int*)d_in[1];
  const int*   h1id = (const int*)d_in[2];
  const float* eps[4] = {(const float*)d_in[4],  (const float*)d_in[13], (const float*)d_in[22], (const float*)d_in[31]};
  const float* wa [4] = {(const float*)d_in[5],  (const float*)d_in[14], (const float*)d_in[23], (const float*)d_in[32]};
  const float* ba [4] = {(const float*)d_in[6],  (const float*)d_in[15], (const float*)d_in[24], (const float*)d_in[33]};
  const float* wb [4] = {(const float*)d_in[7],  (const float*)d_in[16], (const float*)d_in[25], (const float*)d_in[34]};
  const float* bb [4] = {(const float*)d_in[8],  (const float*)d_in[17], (const float*)d_in[26], (const float*)d_in[35]};
  const float* g  [4] = {(const float*)d_in[9],  (const float*)d_in[18], (const float*)d_in[27], (const float*)d_in[36]};
  const float* be [4] = {(const float*)d_in[10], (const float*)d_in[19], (const float*)d_in[28], (const float*)d_in[37]};
  const float* m  [4] = {(const float*)d_in[11], (const float*)d_in[20], (const float*)d_in[29], (const float*)d_in[38]};
  const float* v  [4] = {(const float*)d_in[12], (const float*)d_in[21], (const float*)d_in[30], (const float*)d_in[39]};
  const float* wc1 = (const float*)d_in[40];
  const float* bc1 = (const float*)d_in[41];
  const float* pa  = (const float*)d_in[42];
  const float* wc2 = (const float*)d_in[43];
  const float* bc2 = (const float*)d_in[44];

  char* ws = (char*)d_ws;
  u16* wT     = (u16*)(ws + 0);            // 655360 u16 = 1,310,720 B
  int* deg    = (int*)(ws + 1310720);      // 262,144 B
  int* rs     = (int*)(ws + 1572864);      // 65537 ints, pad to 262,400 B
  int* cursor = (int*)(ws + 1835264);      // 262,144 B
  int* csr    = (int*)(ws + 2097408);      // 2,097,152 B
  u16* ybuf   = (u16*)(ws + 4194560);      // 32 MB (y1 / u-scratch)
  u16* tbuf   = (u16*)(ws + 37748992);     // 32 MB (t1)
  u16* hbuf   = (u16*)(ws + 71303424);     // 32 MB (h)
  u16* u4     = (u16*)(ws + 104857856);    // 3.2 MB  (raw agg, 6400 rows)

  // wT sub-offsets (u16 elements)
  u16* w1aT = wT;            // [256][512]
  u16* w1bT = wT + 131072;
  u16* w2aT = wT + 196608;
  u16* w2bT = wT + 262144;
  u16* w3aT = wT + 327680;
  u16* w3bT = wT + 393216;
  u16* w4aT = wT + 458752;
  u16* w4bT = wT + 524288;
  u16* wc1T = wT + 589824;

  hipMemsetAsync(deg, 0, 65536 * 4, stream);
  hipMemsetAsync(cursor, 0, 65536 * 4, stream);
  prep_hist_k<<<4608, 256, 0, stream>>>(wa[0], wb[0], wa[1], wb[1], wa[2], wb[2],
      wa[3], wb[3], wc1, wT, A + NE, deg);
  scan_k<<<1, 1024, 0, stream>>>(deg, rs);

  // layer 1 GEMM (feat @ w1a) with CSR scatter folded into the same grid
  gemm1_scat_k<<<1536, 512, 0, stream>>>(feat, w1aT, ybuf,
      A, A + NE, rs, cursor, csr);

  // layer 1 rest: t1 = relu(agg(y1)+ba1); h1 = relu(BN(t1@w1b+bb1))
  agg_k<0,0><<<NN / 8, 256, 0, stream>>>(ybuf, rs, csr, eps[0], ba[0], nullptr, tbuf);
  gemm_k<1,1,256><<<512, 512, 0, stream>>>(tbuf, w1bT, hbuf,
      g[0], be[0], m[0], v[0], bb[0]);

  // layers 2,3 (linearity-swapped): u = agg_eps(h); h' = relu(BN(relu(u@wa+ba)@wb+bb))
  agg_k<0,1><<<NN / 8, 256, 0, stream>>>(hbuf, rs, csr, eps[1], nullptr, nullptr, ybuf);
  dual_k<<<512, 512, 0, stream>>>(ybuf, w2aT, ba[1], w2bT,
      g[1], be[1], m[1], v[1], bb[1], hbuf);
  agg_k<0,1><<<NN / 8, 256, 0, stream>>>(hbuf, rs, csr, eps[2], nullptr, nullptr, ybuf);
  dual_k<<<512, 512, 0, stream>>>(ybuf, w3aT, ba[2], w3bT,
      g[2], be[2], m[2], v[2], bb[2], hbuf);

  // layer 4 (order-swapped): u4 = agg_eps4(h3) at the 6400 gathered rows,
  // then fused tail: relu(@w4a+ba4) -> BN(@w4b+bb4) -> PReLU(@wc1+bc1) -> @wc2+bc2
  agg_k<1,1><<<800, 256, 0, stream>>>(hbuf, rs, csr, eps[3], nullptr, h1id, u4);
  tail_k<<<50, 512, 0, stream>>>(u4, w4aT, ba[3], w4bT,
      g[3], be[3], m[3], v[3], bb[3],
      wc1T, bc1, pa, wc2, bc2, (float*)d_out);

  (void)in_sizes; (void)n_in; (void)out_size; (void)ws_size;
}